// Round 10
// baseline (156.735 us; speedup 1.0000x reference)
//
#include <hip/hip_runtime.h>
#include <hip/hip_bf16.h>

namespace {

constexpr int kB = 8, kT = 64, kE = 4, kD = 256, kH = 1024;

typedef float floatx4 __attribute__((ext_vector_type(4)));

__device__ __forceinline__ float gelu_exact(float v) {
  return 0.5f * v * (1.0f + erff(v * 0.70710678118654752f));
}

__device__ __forceinline__ float4 ntload4(const float4* p) {
  const floatx4 v = __builtin_nontemporal_load(reinterpret_cast<const floatx4*>(p));
  return make_float4(v.x, v.y, v.z, v.w);
}

// grid = 256 (one block per (t,e)); 4 waves; wave w privately owns h-chunk
// [256w, 256w+256). hid lives in registers; the only barrier is after x-staging.
__global__ __launch_bounds__(256, 1)
void moe_ffn_kernel(const float* __restrict__ x,
                    const float* __restrict__ fc1,
                    const float* __restrict__ b1,
                    const float* __restrict__ fc2,
                    const float* __restrict__ b2,
                    const float* __restrict__ Wr,
                    const float* __restrict__ br,
                    float* __restrict__ out) {
  __shared__ float xs[kB][kD];   // 8 KB

  const int tid  = threadIdx.x;
  const int te   = blockIdx.x;
  const int t    = te >> 2;
  const int wave = tid >> 6, lane = tid & 63;
  const int c    = wave;          // private h-chunk index

  // ---- stage x[b, t, :] into LDS as float4 ----
  {
    const float4* __restrict__ xsrc = reinterpret_cast<const float4*>(x);
    float4* xdst = reinterpret_cast<float4*>(&xs[0][0]);
#pragma unroll
    for (int i = 0; i < 2; ++i) {
      const int f = i * 256 + tid;           // 0..511 float4s
      const int b = f >> 6, d4 = f & 63;
      xdst[f] = xsrc[(size_t)(b * kT + t) * (kD / 4) + d4];
    }
  }
  __syncthreads();   // the only block-wide barrier

  // ---- router gates, computed per wave (all lanes end with all 8 gates) ----
  float gates[kB];
  {
    const float* __restrict__ wr = Wr + (size_t)te * kD;
    const float w0 = wr[lane], w1 = wr[lane + 64], w2 = wr[lane + 128], w3 = wr[lane + 192];
    const float brv = br[te];
#pragma unroll
    for (int b = 0; b < kB; ++b) {
      float p = xs[b][lane] * w0 + xs[b][lane + 64] * w1 +
                xs[b][lane + 128] * w2 + xs[b][lane + 192] * w3;
#pragma unroll
      for (int off = 32; off; off >>= 1) p += __shfl_xor(p, off);
      const float g = p + brv;
      gates[b] = g > 0.0f ? g : 0.0f;
    }
  }

  // ---- phase 1: lane owns h = 256c + 4*lane .. +3; accumulate over all d ----
  // fc1 loads: NT dwordx4, 1 KB per wave-instr.
  float4 hid[kB];
  {
    float4 a[kB];
#pragma unroll
    for (int b = 0; b < kB; ++b) a[b] = make_float4(0.f, 0.f, 0.f, 0.f);
    const float4* __restrict__ wp =
        reinterpret_cast<const float4*>(fc1 + (size_t)te * (kD * kH));  // [d][kH/4]
    const int hq = c * 64 + lane;
#pragma unroll 2
    for (int dg = 0; dg < 64; ++dg) {
      const int d = dg * 4;
      const float4 wv0 = ntload4(wp + (size_t)(d + 0) * (kH / 4) + hq);
      const float4 wv1 = ntload4(wp + (size_t)(d + 1) * (kH / 4) + hq);
      const float4 wv2 = ntload4(wp + (size_t)(d + 2) * (kH / 4) + hq);
      const float4 wv3 = ntload4(wp + (size_t)(d + 3) * (kH / 4) + hq);
#pragma unroll
      for (int b = 0; b < kB; ++b) {
        const float4 xv = *reinterpret_cast<const float4*>(&xs[b][d]);
        a[b].x = fmaf(xv.x, wv0.x, a[b].x);
        a[b].y = fmaf(xv.x, wv0.y, a[b].y);
        a[b].z = fmaf(xv.x, wv0.z, a[b].z);
        a[b].w = fmaf(xv.x, wv0.w, a[b].w);
        a[b].x = fmaf(xv.y, wv1.x, a[b].x);
        a[b].y = fmaf(xv.y, wv1.y, a[b].y);
        a[b].z = fmaf(xv.y, wv1.z, a[b].z);
        a[b].w = fmaf(xv.y, wv1.w, a[b].w);
        a[b].x = fmaf(xv.z, wv2.x, a[b].x);
        a[b].y = fmaf(xv.z, wv2.y, a[b].y);
        a[b].z = fmaf(xv.z, wv2.z, a[b].z);
        a[b].w = fmaf(xv.z, wv2.w, a[b].w);
        a[b].x = fmaf(xv.w, wv3.x, a[b].x);
        a[b].y = fmaf(xv.w, wv3.y, a[b].y);
        a[b].z = fmaf(xv.w, wv3.z, a[b].z);
        a[b].w = fmaf(xv.w, wv3.w, a[b].w);
      }
    }
    // bias + gelu, all in registers
    const float4 bias =
        *reinterpret_cast<const float4*>(&b1[(size_t)te * kH + c * 256 + 4 * lane]);
#pragma unroll
    for (int b = 0; b < kB; ++b) {
      hid[b].x = gelu_exact(a[b].x + bias.x);
      hid[b].y = gelu_exact(a[b].y + bias.y);
      hid[b].z = gelu_exact(a[b].z + bias.z);
      hid[b].w = gelu_exact(a[b].w + bias.w);
    }
  }

  // ---- phase 2: wave streams its chunk's 256 fc2 rows (sequential 256 KB) ----
  // hid[b][h] broadcast from owning lane via __shfl (uniform src lane).
  float4 acc2[kB];
#pragma unroll
  for (int b = 0; b < kB; ++b) acc2[b] = make_float4(0.f, 0.f, 0.f, 0.f);
  {
    const float4* __restrict__ wp2 =
        reinterpret_cast<const float4*>(fc2 + (size_t)te * (kH * kD)) + lane;  // [h][kD/4]
#pragma unroll 2
    for (int hg = 0; hg < 64; ++hg) {
      const int hrow = c * 256 + hg * 4;
      const float4 wv0 = ntload4(wp2 + (size_t)(hrow + 0) * (kD / 4));
      const float4 wv1 = ntload4(wp2 + (size_t)(hrow + 1) * (kD / 4));
      const float4 wv2 = ntload4(wp2 + (size_t)(hrow + 2) * (kD / 4));
      const float4 wv3 = ntload4(wp2 + (size_t)(hrow + 3) * (kD / 4));
#pragma unroll
      for (int b = 0; b < kB; ++b) {
        const float hx = __shfl(hid[b].x, hg);
        const float hy = __shfl(hid[b].y, hg);
        const float hz = __shfl(hid[b].z, hg);
        const float hw = __shfl(hid[b].w, hg);
        acc2[b].x = fmaf(hx, wv0.x, acc2[b].x);
        acc2[b].y = fmaf(hx, wv0.y, acc2[b].y);
        acc2[b].z = fmaf(hx, wv0.z, acc2[b].z);
        acc2[b].w = fmaf(hx, wv0.w, acc2[b].w);
        acc2[b].x = fmaf(hy, wv1.x, acc2[b].x);
        acc2[b].y = fmaf(hy, wv1.y, acc2[b].y);
        acc2[b].z = fmaf(hy, wv1.z, acc2[b].z);
        acc2[b].w = fmaf(hy, wv1.w, acc2[b].w);
        acc2[b].x = fmaf(hz, wv2.x, acc2[b].x);
        acc2[b].y = fmaf(hz, wv2.y, acc2[b].y);
        acc2[b].z = fmaf(hz, wv2.z, acc2[b].z);
        acc2[b].w = fmaf(hz, wv2.w, acc2[b].w);
        acc2[b].x = fmaf(hw, wv3.x, acc2[b].x);
        acc2[b].y = fmaf(hw, wv3.y, acc2[b].y);
        acc2[b].z = fmaf(hw, wv3.z, acc2[b].z);
        acc2[b].w = fmaf(hw, wv3.w, acc2[b].w);
      }
    }
  }

  // ---- epilogue: lane owns d = 4*lane..+3; gate-scale; accumulate over e,chunk ----
  {
    const int d0 = 4 * lane;
    float4 b2v = make_float4(0.f, 0.f, 0.f, 0.f);
    if (wave == 0) b2v = *reinterpret_cast<const float4*>(&b2[(size_t)te * kD + d0]);
#pragma unroll
    for (int b = 0; b < kB; ++b) {
      const float g = gates[b];
      float* o = &out[((size_t)b * kT + t) * kD + d0];
      atomicAdd(o + 0, g * (acc2[b].x + b2v.x));
      atomicAdd(o + 1, g * (acc2[b].y + b2v.y));
      atomicAdd(o + 2, g * (acc2[b].z + b2v.z));
      atomicAdd(o + 3, g * (acc2[b].w + b2v.w));
    }
    if (wave == 0 && lane == 0) {
      float gs = 0.f;
#pragma unroll
      for (int b = 0; b < kB; ++b) gs += gates[b];
      atomicAdd(&out[(size_t)kB * kT * kD], 0.01f * gs * (1.0f / (kB * kT)));
    }
  }
}

}  // namespace

extern "C" void kernel_launch(void* const* d_in, const int* in_sizes, int n_in,
                              void* d_out, int out_size, void* d_ws, size_t ws_size,
                              hipStream_t stream) {
  const float* x   = (const float*)d_in[0];
  const float* fc1 = (const float*)d_in[1];
  const float* b1  = (const float*)d_in[2];
  const float* fc2 = (const float*)d_in[3];
  const float* b2  = (const float*)d_in[4];
  const float* Wr  = (const float*)d_in[5];
  const float* br  = (const float*)d_in[6];
  float* out = (float*)d_out;

  // Zero the accumulation target every call (graph replays must be
  // deterministic; harness does not re-poison between replays).
  (void)hipMemsetAsync(d_out, 0, (size_t)out_size * sizeof(float), stream);

  moe_ffn_kernel<<<dim3(kT * kE), dim3(256), 0, stream>>>(
      x, fc1, b1, fc2, b2, Wr, br, out);
}